// Round 10
// baseline (841.597 us; speedup 1.0000x reference)
//
#include <hip/hip_runtime.h>
#include <hip/hip_bf16.h>
#include <math.h>

typedef __attribute__((ext_vector_type(8))) short short8;
typedef __attribute__((ext_vector_type(4))) float f32x4;
typedef unsigned short ushort_t;
typedef unsigned int uint_t;

typedef __attribute__((address_space(1))) const void gvoid_t;
typedef __attribute__((address_space(3))) void lvoid_t;

#define VTILES 125

static __device__ __forceinline__ ushort_t f2b(float f){
  __hip_bfloat16 h = __float2bfloat16(f);
  return *reinterpret_cast<ushort_t*>(&h);
}
static __device__ __forceinline__ float b2f(ushort_t u){
  __hip_bfloat16 h = *reinterpret_cast<__hip_bfloat16*>(&u);
  return __bfloat162float(h);
}
static __device__ __forceinline__ float sigmoidf_(float x){ return 1.0f/(1.0f+__expf(-x)); }

// ---------- transpose + f32->bf16 convert: dst[c][dcoloff + r] = src[r][c] ----------
__global__ void k_transpose_cvt(const float* __restrict__ src, ushort_t* __restrict__ dst,
                                int C, int dstride, int dcoloff) {
  __shared__ ushort_t tile[64][72];
  int cb = blockIdx.x * 64, rb = blockIdx.y * 64;
  int tid = threadIdx.x;
  for (int it = 0; it < 4; ++it) {
    int e = tid + it*256;
    int row = e >> 4;
    int seg = e & 15;
    float4 v = *reinterpret_cast<const float4*>(&src[(size_t)(rb+row)*C + cb + seg*4]);
    tile[seg*4+0][row] = f2b(v.x);
    tile[seg*4+1][row] = f2b(v.y);
    tile[seg*4+2][row] = f2b(v.z);
    tile[seg*4+3][row] = f2b(v.w);
  }
  __syncthreads();
  for (int it = 0; it < 2; ++it) {
    int e = tid + it*256;
    int cl = e >> 3;
    int seg = e & 7;
    uint4 v = *reinterpret_cast<uint4*>(&tile[cl][seg*8]);
    *reinterpret_cast<uint4*>(&dst[(size_t)(cb+cl)*dstride + dcoloff + rb + seg*8]) = v;
  }
}

// ---------- features [n][d][16] f32 -> fBT [(n*16+p)][d] bf16 ----------
__global__ void k_featT(const float* __restrict__ feat, ushort_t* __restrict__ fBT) {
  __shared__ ushort_t t[16][264];
  int n = blockIdx.x;
  int tid = threadIdx.x;
  for (int it = 0; it < 4; ++it) {
    int d = it*256 + tid;
    const float* src = &feat[((size_t)n*1024 + d)*16];
    #pragma unroll
    for (int q = 0; q < 4; ++q) {
      float4 v = *reinterpret_cast<const float4*>(&src[q*4]);
      t[q*4+0][tid] = f2b(v.x);
      t[q*4+1][tid] = f2b(v.y);
      t[q*4+2][tid] = f2b(v.z);
      t[q*4+3][tid] = f2b(v.w);
    }
    __syncthreads();
    #pragma unroll
    for (int w = 0; w < 2; ++w) {
      int e = tid + w*256;
      int p = e >> 5;
      int seg = e & 31;
      uint4 v = *reinterpret_cast<uint4*>(&t[p][seg*8]);
      *reinterpret_cast<uint4*>(&fBT[((size_t)n*16 + p)*1024 + it*256 + seg*8]) = v;
    }
    __syncthreads();
  }
}

// ---------- embedding gather -> bf16 ----------
__global__ void k_embed(const int* __restrict__ captions, const float* __restrict__ W_embed,
                        ushort_t* __restrict__ xb) {
  int e = (blockIdx.x*256 + threadIdx.x) * 4;
  int nt = e >> 9;
  int n = nt >> 5, t = nt & 31;
  int col = e & 511;
  int tok = captions[n*33 + t];
  float4 v = *reinterpret_cast<const float4*>(&W_embed[(size_t)tok*512 + col]);
  ushort4 o; o.x=f2b(v.x); o.y=f2b(v.y); o.z=f2b(v.z); o.w=f2b(v.w);
  *reinterpret_cast<ushort4*>(&xb[e]) = o;
}

// ---------- A_flat/Abt = WprojT @ fBT^T + b_proj ; h0 fused (MFMA GEMM) ----------
__global__ void k_projmm(const ushort_t* __restrict__ WprojT, const ushort_t* __restrict__ fBT,
                         const float* __restrict__ b_proj, float* __restrict__ A_flat,
                         ushort_t* __restrict__ Abt, float* __restrict__ hbuf) {
  __shared__ ushort_t As[64*64];
  __shared__ ushort_t Bs[64*64];
  int kt = blockIdx.x, nt = blockIdx.y;
  int k0 = kt*64, n0 = nt*64;
  int tid = threadIdx.x;
  int wave = tid>>6, lane = tid&63, lr = lane&15, lg = lane>>4;
  int srow = lane>>3, sxor8 = ((lane&7)^srow)*8;
  f32x4 acc[4];
  #pragma unroll
  for (int nf=0;nf<4;++nf) acc[nf] = (f32x4){0.f,0.f,0.f,0.f};
  for (int kc = 0; kc < 1024; kc += 64){
    __syncthreads();
    #pragma unroll
    for (int u = 0; u < 2; ++u){
      int r0 = wave*16 + u*8;
      const ushort_t* srcA = &WprojT[(size_t)(k0 + r0 + srow)*1024 + kc + sxor8];
      const ushort_t* srcB = &fBT[(size_t)(n0 + r0 + srow)*1024 + kc + sxor8];
      __builtin_amdgcn_global_load_lds((gvoid_t*)srcA, (lvoid_t*)&As[r0*64], 16, 0, 0);
      __builtin_amdgcn_global_load_lds((gvoid_t*)srcB, (lvoid_t*)&Bs[r0*64], 16, 0, 0);
    }
    __syncthreads();
    #pragma unroll
    for (int kk = 0; kk < 2; ++kk){
      int swz = (((kk*4 + lg) ^ (lr & 7)) * 8);
      short8 af = *reinterpret_cast<short8*>(&As[(wave*16 + lr)*64 + swz]);
      #pragma unroll
      for (int nf = 0; nf < 4; ++nf){
        short8 bf = *reinterpret_cast<short8*>(&Bs[(nf*16 + lr)*64 + swz]);
        acc[nf] = __builtin_amdgcn_mfma_f32_16x16x32_bf16(af, bf, acc[nf], 0, 0, 0);
      }
    }
  }
  #pragma unroll
  for (int nf=0;nf<4;++nf){
    int ncol = n0 + nf*16 + lr;
    int nidx = ncol >> 4, p = ncol & 15;
    ushort4 ab;
    #pragma unroll
    for (int r=0;r<4;++r){
      int kh = k0 + wave*16 + lg*4 + r;
      float val = acc[nf][r] + b_proj[kh];
      A_flat[((size_t)nidx*1024 + kh)*16 + p] = val;
      (&ab.x)[r] = f2b(val);
      float s = val;
      s += __shfl_xor(s, 1, 64);
      s += __shfl_xor(s, 2, 64);
      s += __shfl_xor(s, 4, 64);
      s += __shfl_xor(s, 8, 64);
      if (lr == 0) hbuf[(nt*4 + nf)*1024 + kh] = s * (1.f/16.f);
    }
    *reinterpret_cast<ushort4*>(&Abt[(size_t)ncol*1024 + k0 + wave*16 + lg*4]) = ab;
  }
}

// ---------- P3[n][j][p] = sum_k Wattn[k][j] * A_flat[n][k][p]  (MFMA GEMM) ----------
__global__ void k_pmm(const ushort_t* __restrict__ WcatT, const ushort_t* __restrict__ Abt,
                      ushort_t* __restrict__ P3) {
  __shared__ ushort_t As[64*64];
  __shared__ ushort_t Bs[64*64];
  __shared__ ushort_t Dt2[64][72];
  int jt = blockIdx.x, nt = blockIdx.y;
  int j0 = jt*64, n0 = nt*64;
  int tid = threadIdx.x;
  int wave = tid>>6, lane = tid&63, lr = lane&15, lg = lane>>4;
  int srow = lane>>3, sxor8 = ((lane&7)^srow)*8;
  f32x4 acc[4];
  #pragma unroll
  for (int nf=0;nf<4;++nf) acc[nf] = (f32x4){0.f,0.f,0.f,0.f};
  for (int kc = 0; kc < 1024; kc += 64){
    __syncthreads();
    #pragma unroll
    for (int u = 0; u < 2; ++u){
      int r0 = wave*16 + u*8;
      const ushort_t* srcA = &WcatT[(size_t)(j0 + r0 + srow)*2560 + 1536 + kc + sxor8];
      const ushort_t* srcB = &Abt[(size_t)(n0 + r0 + srow)*1024 + kc + sxor8];
      __builtin_amdgcn_global_load_lds((gvoid_t*)srcA, (lvoid_t*)&As[r0*64], 16, 0, 0);
      __builtin_amdgcn_global_load_lds((gvoid_t*)srcB, (lvoid_t*)&Bs[r0*64], 16, 0, 0);
    }
    __syncthreads();
    #pragma unroll
    for (int kk = 0; kk < 2; ++kk){
      int swz = (((kk*4 + lg) ^ (lr & 7)) * 8);
      short8 af = *reinterpret_cast<short8*>(&As[(wave*16 + lr)*64 + swz]);
      #pragma unroll
      for (int nf = 0; nf < 4; ++nf){
        short8 bf = *reinterpret_cast<short8*>(&Bs[(nf*16 + lr)*64 + swz]);
        acc[nf] = __builtin_amdgcn_mfma_f32_16x16x32_bf16(af, bf, acc[nf], 0, 0, 0);
      }
    }
  }
  __syncthreads();
  #pragma unroll
  for (int nf=0;nf<4;++nf)
    #pragma unroll
    for (int r=0;r<4;++r)
      Dt2[wave*16 + lg*4 + r][nf*16 + lr] = f2b(acc[nf][r]);
  __syncthreads();
  #pragma unroll
  for (int it=0; it<2; ++it){
    int e = it*256 + tid;
    int row = e >> 3, seg = e & 7;
    uint4 v = *reinterpret_cast<uint4*>(&Dt2[row][seg*8]);
    *reinterpret_cast<uint4*>(&P3[(((size_t)nt*4 + (seg>>1))*4096 + j0 + row)*16 + (seg&1)*8]) = v;
  }
}

// ---------- xpre[nt][j] = xb @ Wx ----------
__global__ void k_xmm(const ushort_t* __restrict__ WcatT, const ushort_t* __restrict__ xb,
                      ushort_t* __restrict__ xpre) {
  __shared__ ushort_t As[64*64];
  __shared__ ushort_t Bs[64*64];
  __shared__ float Dt[64][68];
  int jt = blockIdx.x, mt = blockIdx.y;
  int j0 = jt*64, m0 = mt*64;
  int tid = threadIdx.x;
  int wave = tid>>6, lane = tid&63, lr = lane&15, lg = lane>>4;
  int srow = lane>>3, sxor8 = ((lane&7)^srow)*8;
  f32x4 acc[4];
  #pragma unroll
  for (int nf=0;nf<4;++nf) acc[nf] = (f32x4){0.f,0.f,0.f,0.f};
  for (int kc = 0; kc < 512; kc += 64){
    __syncthreads();
    #pragma unroll
    for (int u = 0; u < 2; ++u){
      int r0 = wave*16 + u*8;
      const ushort_t* srcA = &WcatT[(size_t)(j0 + r0 + srow)*2560 + kc + sxor8];
      const ushort_t* srcB = &xb[(size_t)(m0 + r0 + srow)*512 + kc + sxor8];
      __builtin_amdgcn_global_load_lds((gvoid_t*)srcA, (lvoid_t*)&As[r0*64], 16, 0, 0);
      __builtin_amdgcn_global_load_lds((gvoid_t*)srcB, (lvoid_t*)&Bs[r0*64], 16, 0, 0);
    }
    __syncthreads();
    #pragma unroll
    for (int kk = 0; kk < 2; ++kk){
      int swz = (((kk*4 + lg) ^ (lr & 7)) * 8);
      short8 af = *reinterpret_cast<short8*>(&As[(wave*16 + lr)*64 + swz]);
      #pragma unroll
      for (int nf = 0; nf < 4; ++nf){
        short8 bf = *reinterpret_cast<short8*>(&Bs[(nf*16 + lr)*64 + swz]);
        acc[nf] = __builtin_amdgcn_mfma_f32_16x16x32_bf16(af, bf, acc[nf], 0, 0, 0);
      }
    }
  }
  __syncthreads();
  #pragma unroll
  for (int nf=0; nf<4; ++nf)
    #pragma unroll
    for (int r=0;r<4;++r)
      Dt[nf*16+lr][wave*16 + lg*4 + r] = acc[nf][r];
  __syncthreads();
  #pragma unroll
  for (int it=0; it<4; ++it){
    int e = tid + it*256;
    int nrow = e >> 4, seg = e & 15;
    float4 v = *reinterpret_cast<float4*>(&Dt[nrow][seg*4]);
    ushort4 o; o.x=f2b(v.x); o.y=f2b(v.y); o.z=f2b(v.z); o.w=f2b(v.w);
    *reinterpret_cast<ushort4*>(&xpre[(size_t)(m0+nrow)*4096 + j0 + seg*4]) = o;
  }
}

// ---------- fused step: wv softmax + full-K mm (j-quadrant slices) + gates + spart ----------
// Block (jt, nh): j-set = {g*1024 + jt*16 + [0,16)}, gates (n in nh*32+[0,32), k in jt*16+[0,16)).
__global__ void __launch_bounds__(256, 4)
k_fstep(int i, const ushort_t* __restrict__ xpre, const float* __restrict__ bvec,
        const ushort_t* __restrict__ P3, const float* __restrict__ A_flat,
        const float* __restrict__ hbuf, float* __restrict__ cbuf,
        const float* __restrict__ sp_rd, float* __restrict__ sp_wr,
        ushort_t* __restrict__ hbf, ushort_t* __restrict__ hall,
        const ushort_t* __restrict__ WcatT) {
  __shared__ ushort_t A_lds[64*64];      // 4 quadrants x 16 j-rows x 64k
  __shared__ ushort_t B_lds[32*64];      // 32 n-rows x 64k
  __shared__ float aq[4][16][34];        // [g][k_local][n_local]
  __shared__ float wvLds[32][16];
  const int jt = blockIdx.x, nh = blockIdx.y;
  const int tid = threadIdx.x;
  const int w = tid >> 6, lane = tid & 63;
  const int lr = lane & 15, lg = lane >> 4;
  const int srow = lane >> 3, sxor8 = ((lane & 7) ^ srow) * 8;
  const int k_local = tid & 15, kg = jt*16 + k_local;
  const int ng0 = tid >> 4;

  if (i > 0) {
    // ---- wv: reduce 64 spart partials + softmax over p (this n-half) ----
    float sv[2];
    #pragma unroll
    for (int e = 0; e < 2; ++e){
      int idx = tid*2 + e;
      int nl = idx >> 4, p = idx & 15;
      const float* src = &sp_rd[(((size_t)(nh*32 + nl))*16 + p)*64];
      float s = 0.f;
      #pragma unroll
      for (int u = 0; u < 16; ++u){
        float4 v = *reinterpret_cast<const float4*>(&src[u*4]);
        s += v.x + v.y + v.z + v.w;
      }
      sv[e] = s * (1.f/32.f);
    }
    float m = fmaxf(sv[0], sv[1]);
    #pragma unroll
    for (int d = 1; d < 8; d <<= 1) m = fmaxf(m, __shfl_xor(m, d, 64));
    float e0 = __expf(sv[0]-m), e1 = __expf(sv[1]-m);
    float ssum = e0 + e1;
    #pragma unroll
    for (int d = 1; d < 8; d <<= 1) ssum += __shfl_xor(ssum, d, 64);
    float inv = 1.f/ssum;
    {
      int nl = (tid*2) >> 4, p0 = (tid*2) & 15;
      wvLds[nl][p0] = e0*inv;
      wvLds[nl][p0+1] = e1*inv;
    }
    // ---- mm: a[j-set][n-half] = Wh^T-slice @ h, full K=1024 ----
    f32x4 acc[2];
    acc[0] = (f32x4){0.f,0.f,0.f,0.f};
    acc[1] = (f32x4){0.f,0.f,0.f,0.f};
    for (int kc = 0; kc < 1024; kc += 64){
      __syncthreads();
      #pragma unroll
      for (int u = 0; u < 2; ++u){
        const ushort_t* sA = &WcatT[((size_t)(w*1024 + jt*16 + u*8 + srow))*2560 + 512 + kc + sxor8];
        __builtin_amdgcn_global_load_lds((gvoid_t*)sA, (lvoid_t*)&A_lds[(w*16 + u*8)*64], 16, 0, 0);
      }
      {
        const ushort_t* sB = &hbf[((size_t)(nh*32 + w*8 + srow))*1024 + kc + sxor8];
        __builtin_amdgcn_global_load_lds((gvoid_t*)sB, (lvoid_t*)&B_lds[(w*8)*64], 16, 0, 0);
      }
      __syncthreads();
      #pragma unroll
      for (int kk = 0; kk < 2; ++kk){
        int swz = (((kk*4 + lg) ^ (lr & 7)) * 8);
        short8 af = *reinterpret_cast<short8*>(&A_lds[(w*16 + lr)*64 + swz]);
        #pragma unroll
        for (int nf = 0; nf < 2; ++nf){
          short8 bf = *reinterpret_cast<short8*>(&B_lds[(nf*16 + lr)*64 + swz]);
          acc[nf] = __builtin_amdgcn_mfma_f32_16x16x32_bf16(af, bf, acc[nf], 0, 0, 0);
        }
      }
    }
    __syncthreads();
    // D-layout: col = n_local = nf*16+lr, row = j_local = lg*4+r (quadrant = wave)
    #pragma unroll
    for (int nf = 0; nf < 2; ++nf)
      #pragma unroll
      for (int r = 0; r < 4; ++r)
        aq[w][lg*4 + r][nf*16 + lr] = acc[nf][r];
    __syncthreads();
  }

  // ---- gates (or h0) + spart partials ----
  #pragma unroll
  for (int q = 0; q < 2; ++q){
    int nl = ng0 + q*16;
    int n = nh*32 + nl;
    float hv;
    if (i == 0){
      hv = hbuf[n*1024 + kg];
      cbuf[n*1024 + kg] = hv;
      hbf[n*1024 + kg] = f2b(hv);
    } else {
      float av[4];
      #pragma unroll
      for (int g = 0; g < 4; ++g){
        int j = g*1024 + kg;
        float x = bvec[j] + b2f(xpre[((size_t)n*32 + (i-1))*4096 + j]) + aq[g][k_local][nl];
        const ushort_t* pp = &P3[((size_t)n*4096 + j)*16];
        short8 p0 = *reinterpret_cast<const short8*>(pp);
        short8 p1 = *reinterpret_cast<const short8*>(pp + 8);
        #pragma unroll
        for (int p = 0; p < 8; ++p) x += wvLds[nl][p]   * b2f((ushort_t)p0[p]);
        #pragma unroll
        for (int p = 0; p < 8; ++p) x += wvLds[nl][8+p] * b2f((ushort_t)p1[p]);
        av[g] = x;
      }
      float ig = sigmoidf_(av[0]), fg = sigmoidf_(av[1]);
      float og = sigmoidf_(av[2]), gg = tanhf(av[3]);
      float c = fg*cbuf[n*1024 + kg] + ig*gg;
      hv = og*tanhf(c);
      cbuf[n*1024 + kg] = c;
      hall[((size_t)n*32 + (i-1))*1024 + kg] = f2b(hv);
      if (i < 32) hbf[n*1024 + kg] = f2b(hv);
    }
    if (i < 32){
      float sacc[16];
      const float* An = &A_flat[((size_t)n*1024 + kg)*16];
      #pragma unroll
      for (int p = 0; p < 16; p += 4){
        float4 a4 = *reinterpret_cast<const float4*>(&An[p]);
        sacc[p] = hv*a4.x; sacc[p+1] = hv*a4.y; sacc[p+2] = hv*a4.z; sacc[p+3] = hv*a4.w;
      }
      #pragma unroll
      for (int d = 1; d < 16; d <<= 1)
        #pragma unroll
        for (int p = 0; p < 16; ++p) sacc[p] += __shfl_xor(sacc[p], d, 64);
      float outv = 0.f;
      #pragma unroll
      for (int p = 0; p < 16; ++p) if (p == k_local) outv = sacc[p];
      sp_wr[((size_t)n*16 + k_local)*64 + jt] = outv;
    }
  }
}

// ---------- scores: 256v x 128r tile, 2-phase barriers, 8 waves, fused partial lse ----------
__global__ void __launch_bounds__(512, 4)
k_score(const ushort_t* __restrict__ WoutT, const ushort_t* __restrict__ hall,
        const float* __restrict__ b_out,
        float* __restrict__ pmax, float* __restrict__ psum) {
  __shared__ ushort_t A_lds[256*64];
  __shared__ ushort_t B_lds[128*64];
  __shared__ float bLds[256];
  __shared__ float pmLds[2][128];
  __shared__ float psLds[2][128];

  int bid = blockIdx.x;
  int wg = (bid & 7) * 250 + (bid >> 3);
  int vb = wg >> 4, rb = wg & 15;
  size_t v0 = (size_t)vb * 256, r0 = (size_t)rb * 128;
  int tid = threadIdx.x;
  int wid = tid >> 6, lane = tid & 63;
  int wr = wid >> 2, wc = wid & 3;
  int lr = lane & 15, lg = lane >> 4;
  int srow = lane >> 3, sxor8 = ((lane & 7) ^ srow) * 8;

  if (tid < 256) bLds[tid] = b_out[v0 + tid];

  const ushort_t* Abase = WoutT + v0*1024 + (size_t)srow*1024 + sxor8;
  const ushort_t* Bbase = hall  + r0*1024 + (size_t)srow*1024 + sxor8;

  f32x4 acc[8][2];
  #pragma unroll
  for (int fi=0; fi<8; ++fi)
    #pragma unroll
    for (int fj=0; fj<2; ++fj) acc[fi][fj] = (f32x4){0.f,0.f,0.f,0.f};

  for (int kc = 0; kc < 1024; kc += 64) {
    __syncthreads();
    #pragma unroll
    for (int u = 0; u < 4; ++u)
      __builtin_amdgcn_global_load_lds(
        (gvoid_t*)(Abase + (size_t)(u*64 + wid*8)*1024 + kc),
        (lvoid_t*)&A_lds[(u*64 + wid*8)*64], 16, 0, 0);
    #pragma unroll
    for (int u = 0; u < 2; ++u)
      __builtin_amdgcn_global_load_lds(
        (gvoid_t*)(Bbase + (size_t)(u*64 + wid*8)*1024 + kc),
        (lvoid_t*)&B_lds[(u*64 + wid*8)*64], 16, 0, 0);
    __syncthreads();
    #pragma unroll
    for (int kk = 0; kk < 2; ++kk) {
      int swz = ((kk*4 + lg) ^ (lr & 7)) << 3;
      short8 bf0 = *reinterpret_cast<short8*>(&B_lds[(wc*32 + lr)*64 + swz]);
      short8 bf1 = *reinterpret_cast<short8*>(&B_lds[(wc*32 + 16 + lr)*64 + swz]);
      #pragma unroll
      for (int fi = 0; fi < 8; ++fi) {
        short8 af = *reinterpret_cast<short8*>(&A_lds[(wr*128 + fi*16 + lr)*64 + swz]);
        acc[fi][0] = __builtin_amdgcn_mfma_f32_16x16x32_bf16(af, bf0, acc[fi][0], 0,0,0);
        acc[fi][1] = __builtin_amdgcn_mfma_f32_16x16x32_bf16(af, bf1, acc[fi][1], 0,0,0);
      }
    }
  }

  __syncthreads();
  float pm_[2], ps_[2];
  #pragma unroll
  for (int fj=0; fj<2; ++fj){
    float m = -1e30f;
    #pragma unroll
    for (int fi=0; fi<8; ++fi)
      #pragma unroll
      for (int rr=0; rr<4; ++rr){
        float x = acc[fi][fj][rr] + bLds[wr*128 + fi*16 + lg*4 + rr];
        m = fmaxf(m, x);
      }
    float ssum = 0.f;
    #pragma unroll
    for (int fi=0; fi<8; ++fi)
      #pragma unroll
      for (int rr=0; rr<4; ++rr){
        float x = acc[fi][fj][rr] + bLds[wr*128 + fi*16 + lg*4 + rr];
        ssum += __expf(x - m);
      }
    #pragma unroll
    for (int d=16; d<=32; d<<=1){
      float om = __shfl_xor(m, d, 64);
      float os = __shfl_xor(ssum, d, 64);
      float nm = fmaxf(m, om);
      ssum = ssum*__expf(m-nm) + os*__expf(om-nm);
      m = nm;
    }
    pm_[fj] = m; ps_[fj] = ssum;
  }
  if (lg == 0){
    #pragma unroll
    for (int fj=0; fj<2; ++fj){
      pmLds[wr][wc*32 + fj*16 + lr] = pm_[fj];
      psLds[wr][wc*32 + fj*16 + lr] = ps_[fj];
    }
  }
  __syncthreads();
  if (tid < 128){
    float m0 = pmLds[0][tid], m1 = pmLds[1][tid];
    float m = fmaxf(m0, m1);
    float sv = psLds[0][tid]*__expf(m0-m) + psLds[1][tid]*__expf(m1-m);
    pmax[(size_t)(r0 + tid)*VTILES + vb] = m;
    psum[(size_t)(r0 + tid)*VTILES + vb] = sv;
  }
}

// ---------- target score + lse combine -> per-row masked nll ----------
__global__ void k_nll(const ushort_t* __restrict__ hall, const ushort_t* __restrict__ WoutT,
                      const float* __restrict__ b_out, const int* __restrict__ captions,
                      const float* __restrict__ pmax, const float* __restrict__ psum,
                      float* __restrict__ row_loss) {
  int tid = threadIdx.x;
  int wave = tid>>6, lane = tid&63;
  int r = blockIdx.x*4 + wave;
  int n = r>>5, t = r&31;
  int y = captions[n*33 + t + 1];
  const ushort_t* hrow = hall + (size_t)r*1024;
  const ushort_t* wrow = WoutT + (size_t)y*1024;
  float dot = 0.f;
  #pragma unroll
  for (int i=0;i<2;++i){
    int off = lane*8 + i*512;
    short8 hv = *reinterpret_cast<const short8*>(&hrow[off]);
    short8 wv = *reinterpret_cast<const short8*>(&wrow[off]);
    #pragma unroll
    for (int e2=0;e2<8;++e2) dot += b2f((ushort_t)hv[e2])*b2f((ushort_t)wv[e2]);
  }
  float m = -1e30f, s = 0.f;
  for (int j = lane; j < VTILES; j += 64){
    float mj = pmax[(size_t)r*VTILES + j];
    float sj = psum[(size_t)r*VTILES + j];
    float nm = fmaxf(m, mj);
    s = s*__expf(m-nm) + sj*__expf(mj-nm);
    m = nm;
  }
  #pragma unroll
  for (int d=32; d>=1; d>>=1){
    dot += __shfl_xor(dot, d, 64);
    float om = __shfl_xor(m, d, 64);
    float os = __shfl_xor(s, d, 64);
    float nm = fmaxf(m, om);
    s = s*__expf(m-nm) + os*__expf(om-nm);
    m = nm;
  }
  if (lane==0){
    float lse = m + __logf(s);
    row_loss[r] = (y != 0) ? (lse - (dot + b_out[y])) : 0.f;
  }
}

// ---------- final deterministic sum ----------
__global__ void k_final(const float* __restrict__ row_loss, float* __restrict__ out) {
  __shared__ float red[256];
  int tid = threadIdx.x;
  float s = 0.f;
  #pragma unroll
  for (int i=0;i<8;++i) s += row_loss[tid + i*256];
  red[tid] = s;
  __syncthreads();
  for (int off=128; off>=1; off>>=1){
    if (tid<off) red[tid] += red[tid+off];
    __syncthreads();
  }
  if (tid==0) out[0] = red[0] * (1.f/64.f);
}

extern "C" void kernel_launch(void* const* d_in, const int* in_sizes, int n_in,
                              void* d_out, int out_size, void* d_ws, size_t ws_size,
                              hipStream_t stream) {
  const float* features = (const float*)d_in[0];
  const int*   captions = (const int*)d_in[1];
  const float* W_embed  = (const float*)d_in[2];
  const float* Wx       = (const float*)d_in[3];
  const float* Wh       = (const float*)d_in[4];
  const float* Wattn    = (const float*)d_in[5];
  const float* b        = (const float*)d_in[6];
  const float* W_proj   = (const float*)d_in[7];
  const float* b_proj   = (const float*)d_in[8];
  const float* W_out    = (const float*)d_in[9];
  const float* b_out    = (const float*)d_in[10];
  float* out = (float*)d_out;

  char* wsp = (char*)d_ws;
  size_t off = 0;
  auto alloc = [&](size_t bytes)->char*{
    char* p = wsp + off; off += (bytes + 255) & ~(size_t)255; return p;
  };
  ushort_t* WcatT  = (ushort_t*)alloc((size_t)4096*2560*2);
  ushort_t* WoutT  = (ushort_t*)alloc((size_t)32000*1024*2);
  ushort_t* WprojT = (ushort_t*)alloc((size_t)1024*1024*2);
  ushort_t* fBT    = (ushort_t*)alloc((size_t)1024*1024*2);
  ushort_t* Abt    = (ushort_t*)alloc((size_t)1024*1024*2);
  float* A_flat    = (float*)alloc((size_t)64*1024*16*4);
  ushort_t* xb     = (ushort_t*)alloc((size_t)64*32*512*2);
  float* hbuf      = (float*)alloc((size_t)64*1024*4);
  ushort_t* P3     = (ushort_t*)alloc((size_t)64*4096*16*2);
  ushort_t* xpre   = (ushort_t*)alloc((size_t)2048*4096*2);
  ushort_t* hbf    = (ushort_t*)alloc((size_t)64*1024*2);
  float* cbuf      = (float*)alloc((size_t)64*1024*4);
  float* spbuf     = (float*)alloc((size_t)2*64*16*64*4);
  ushort_t* hall   = (ushort_t*)alloc((size_t)2048*1024*2);
  float* pmax      = (float*)alloc((size_t)2048*VTILES*4);
  float* psum      = (float*)alloc((size_t)2048*VTILES*4);
  float* row_loss  = (float*)alloc((size_t)2048*4);

  hipLaunchKernelGGL(k_transpose_cvt, dim3(64, 8),   dim3(256), 0, stream, Wx,     WcatT,  4096, 2560, 0);
  hipLaunchKernelGGL(k_transpose_cvt, dim3(64, 16),  dim3(256), 0, stream, Wh,     WcatT,  4096, 2560, 512);
  hipLaunchKernelGGL(k_transpose_cvt, dim3(64, 16),  dim3(256), 0, stream, Wattn,  WcatT,  4096, 2560, 1536);
  hipLaunchKernelGGL(k_transpose_cvt, dim3(500, 16), dim3(256), 0, stream, W_out,  WoutT,  32000, 1024, 0);
  hipLaunchKernelGGL(k_transpose_cvt, dim3(16, 16),  dim3(256), 0, stream, W_proj, WprojT, 1024, 1024, 0);
  hipLaunchKernelGGL(k_featT, dim3(64), dim3(256), 0, stream, features, fBT);
  hipLaunchKernelGGL(k_embed, dim3(1024), dim3(256), 0, stream, captions, W_embed, xb);
  hipLaunchKernelGGL(k_projmm, dim3(16, 16), dim3(256), 0, stream, WprojT, fBT, b_proj, A_flat, Abt, hbuf);
  hipLaunchKernelGGL(k_pmm, dim3(64, 16), dim3(256), 0, stream, WcatT, Abt, P3);
  hipLaunchKernelGGL(k_xmm, dim3(64, 32), dim3(256), 0, stream, WcatT, xb, xpre);

  for (int i = 0; i <= 32; ++i){
    const float* sp_rd = spbuf + ((i+1)&1)*65536;
    float*       sp_wr = spbuf + (i&1)*65536;
    hipLaunchKernelGGL(k_fstep, dim3(64, 2), dim3(256), 0, stream,
                       i, xpre, b, P3, A_flat, hbuf, cbuf, sp_rd, sp_wr, hbf, hall, WcatT);
  }

  hipLaunchKernelGGL(k_score, dim3(2000), dim3(512), 0, stream, WoutT, hall, b_out, pmax, psum);
  hipLaunchKernelGGL(k_nll, dim3(512), dim3(256), 0, stream, hall, WoutT, b_out, captions, pmax, psum, row_loss);
  hipLaunchKernelGGL(k_final, dim3(1), dim3(256), 0, stream, row_loss, out);
}

// Round 11
// 596.576 us; speedup vs baseline: 1.4107x; 1.4107x over previous
//
#include <hip/hip_runtime.h>
#include <hip/hip_bf16.h>
#include <math.h>

typedef __attribute__((ext_vector_type(8))) short short8;
typedef __attribute__((ext_vector_type(4))) float f32x4;
typedef unsigned short ushort_t;
typedef unsigned int uint_t;

typedef __attribute__((address_space(1))) const void gvoid_t;
typedef __attribute__((address_space(3))) void lvoid_t;

#define VTILES 125

static __device__ __forceinline__ ushort_t f2b(float f){
  __hip_bfloat16 h = __float2bfloat16(f);
  return *reinterpret_cast<ushort_t*>(&h);
}
static __device__ __forceinline__ float b2f(ushort_t u){
  __hip_bfloat16 h = *reinterpret_cast<__hip_bfloat16*>(&u);
  return __bfloat162float(h);
}
static __device__ __forceinline__ float sigmoidf_(float x){ return 1.0f/(1.0f+__expf(-x)); }

// ---------- transpose + f32->bf16 convert: dst[c][dcoloff + r] = src[r][c] ----------
__global__ void k_transpose_cvt(const float* __restrict__ src, ushort_t* __restrict__ dst,
                                int C, int dstride, int dcoloff) {
  __shared__ ushort_t tile[64][72];
  int cb = blockIdx.x * 64, rb = blockIdx.y * 64;
  int tid = threadIdx.x;
  for (int it = 0; it < 4; ++it) {
    int e = tid + it*256;
    int row = e >> 4;
    int seg = e & 15;
    float4 v = *reinterpret_cast<const float4*>(&src[(size_t)(rb+row)*C + cb + seg*4]);
    tile[seg*4+0][row] = f2b(v.x);
    tile[seg*4+1][row] = f2b(v.y);
    tile[seg*4+2][row] = f2b(v.z);
    tile[seg*4+3][row] = f2b(v.w);
  }
  __syncthreads();
  for (int it = 0; it < 2; ++it) {
    int e = tid + it*256;
    int cl = e >> 3;
    int seg = e & 7;
    uint4 v = *reinterpret_cast<uint4*>(&tile[cl][seg*8]);
    *reinterpret_cast<uint4*>(&dst[(size_t)(cb+cl)*dstride + dcoloff + rb + seg*8]) = v;
  }
}

// ---------- features [n][d][16] f32 -> fBT [(n*16+p)][d] bf16 ----------
__global__ void k_featT(const float* __restrict__ feat, ushort_t* __restrict__ fBT) {
  __shared__ ushort_t t[16][264];
  int n = blockIdx.x;
  int tid = threadIdx.x;
  for (int it = 0; it < 4; ++it) {
    int d = it*256 + tid;
    const float* src = &feat[((size_t)n*1024 + d)*16];
    #pragma unroll
    for (int q = 0; q < 4; ++q) {
      float4 v = *reinterpret_cast<const float4*>(&src[q*4]);
      t[q*4+0][tid] = f2b(v.x);
      t[q*4+1][tid] = f2b(v.y);
      t[q*4+2][tid] = f2b(v.z);
      t[q*4+3][tid] = f2b(v.w);
    }
    __syncthreads();
    #pragma unroll
    for (int w = 0; w < 2; ++w) {
      int e = tid + w*256;
      int p = e >> 5;
      int seg = e & 31;
      uint4 v = *reinterpret_cast<uint4*>(&t[p][seg*8]);
      *reinterpret_cast<uint4*>(&fBT[((size_t)n*16 + p)*1024 + it*256 + seg*8]) = v;
    }
    __syncthreads();
  }
}

// ---------- embedding gather -> bf16 ----------
__global__ void k_embed(const int* __restrict__ captions, const float* __restrict__ W_embed,
                        ushort_t* __restrict__ xb) {
  int e = (blockIdx.x*256 + threadIdx.x) * 4;
  int nt = e >> 9;
  int n = nt >> 5, t = nt & 31;
  int col = e & 511;
  int tok = captions[n*33 + t];
  float4 v = *reinterpret_cast<const float4*>(&W_embed[(size_t)tok*512 + col]);
  ushort4 o; o.x=f2b(v.x); o.y=f2b(v.y); o.z=f2b(v.z); o.w=f2b(v.w);
  *reinterpret_cast<ushort4*>(&xb[e]) = o;
}

// ---------- A_flat/Abt = WprojT @ fBT^T + b_proj ; h0 fused (MFMA GEMM) ----------
__global__ void k_projmm(const ushort_t* __restrict__ WprojT, const ushort_t* __restrict__ fBT,
                         const float* __restrict__ b_proj, float* __restrict__ A_flat,
                         ushort_t* __restrict__ Abt, float* __restrict__ hbuf) {
  __shared__ ushort_t As[64*64];
  __shared__ ushort_t Bs[64*64];
  int kt = blockIdx.x, nt = blockIdx.y;
  int k0 = kt*64, n0 = nt*64;
  int tid = threadIdx.x;
  int wave = tid>>6, lane = tid&63, lr = lane&15, lg = lane>>4;
  int srow = lane>>3, sxor8 = ((lane&7)^srow)*8;
  f32x4 acc[4];
  #pragma unroll
  for (int nf=0;nf<4;++nf) acc[nf] = (f32x4){0.f,0.f,0.f,0.f};
  for (int kc = 0; kc < 1024; kc += 64){
    __syncthreads();
    #pragma unroll
    for (int u = 0; u < 2; ++u){
      int r0 = wave*16 + u*8;
      const ushort_t* srcA = &WprojT[(size_t)(k0 + r0 + srow)*1024 + kc + sxor8];
      const ushort_t* srcB = &fBT[(size_t)(n0 + r0 + srow)*1024 + kc + sxor8];
      __builtin_amdgcn_global_load_lds((gvoid_t*)srcA, (lvoid_t*)&As[r0*64], 16, 0, 0);
      __builtin_amdgcn_global_load_lds((gvoid_t*)srcB, (lvoid_t*)&Bs[r0*64], 16, 0, 0);
    }
    __syncthreads();
    #pragma unroll
    for (int kk = 0; kk < 2; ++kk){
      int swz = (((kk*4 + lg) ^ (lr & 7)) * 8);
      short8 af = *reinterpret_cast<short8*>(&As[(wave*16 + lr)*64 + swz]);
      #pragma unroll
      for (int nf = 0; nf < 4; ++nf){
        short8 bf = *reinterpret_cast<short8*>(&Bs[(nf*16 + lr)*64 + swz]);
        acc[nf] = __builtin_amdgcn_mfma_f32_16x16x32_bf16(af, bf, acc[nf], 0, 0, 0);
      }
    }
  }
  #pragma unroll
  for (int nf=0;nf<4;++nf){
    int ncol = n0 + nf*16 + lr;
    int nidx = ncol >> 4, p = ncol & 15;
    ushort4 ab;
    #pragma unroll
    for (int r=0;r<4;++r){
      int kh = k0 + wave*16 + lg*4 + r;
      float val = acc[nf][r] + b_proj[kh];
      A_flat[((size_t)nidx*1024 + kh)*16 + p] = val;
      (&ab.x)[r] = f2b(val);
      float s = val;
      s += __shfl_xor(s, 1, 64);
      s += __shfl_xor(s, 2, 64);
      s += __shfl_xor(s, 4, 64);
      s += __shfl_xor(s, 8, 64);
      if (lr == 0) hbuf[(nt*4 + nf)*1024 + kh] = s * (1.f/16.f);
    }
    *reinterpret_cast<ushort4*>(&Abt[(size_t)ncol*1024 + k0 + wave*16 + lg*4]) = ab;
  }
}

// ---------- P3[n][j][p] = sum_k Wattn[k][j] * A_flat[n][k][p]  (MFMA GEMM) ----------
__global__ void k_pmm(const ushort_t* __restrict__ WcatT, const ushort_t* __restrict__ Abt,
                      ushort_t* __restrict__ P3) {
  __shared__ ushort_t As[64*64];
  __shared__ ushort_t Bs[64*64];
  __shared__ ushort_t Dt2[64][72];
  int jt = blockIdx.x, nt = blockIdx.y;
  int j0 = jt*64, n0 = nt*64;
  int tid = threadIdx.x;
  int wave = tid>>6, lane = tid&63, lr = lane&15, lg = lane>>4;
  int srow = lane>>3, sxor8 = ((lane&7)^srow)*8;
  f32x4 acc[4];
  #pragma unroll
  for (int nf=0;nf<4;++nf) acc[nf] = (f32x4){0.f,0.f,0.f,0.f};
  for (int kc = 0; kc < 1024; kc += 64){
    __syncthreads();
    #pragma unroll
    for (int u = 0; u < 2; ++u){
      int r0 = wave*16 + u*8;
      const ushort_t* srcA = &WcatT[(size_t)(j0 + r0 + srow)*2560 + 1536 + kc + sxor8];
      const ushort_t* srcB = &Abt[(size_t)(n0 + r0 + srow)*1024 + kc + sxor8];
      __builtin_amdgcn_global_load_lds((gvoid_t*)srcA, (lvoid_t*)&As[r0*64], 16, 0, 0);
      __builtin_amdgcn_global_load_lds((gvoid_t*)srcB, (lvoid_t*)&Bs[r0*64], 16, 0, 0);
    }
    __syncthreads();
    #pragma unroll
    for (int kk = 0; kk < 2; ++kk){
      int swz = (((kk*4 + lg) ^ (lr & 7)) * 8);
      short8 af = *reinterpret_cast<short8*>(&As[(wave*16 + lr)*64 + swz]);
      #pragma unroll
      for (int nf = 0; nf < 4; ++nf){
        short8 bf = *reinterpret_cast<short8*>(&Bs[(nf*16 + lr)*64 + swz]);
        acc[nf] = __builtin_amdgcn_mfma_f32_16x16x32_bf16(af, bf, acc[nf], 0, 0, 0);
      }
    }
  }
  __syncthreads();
  #pragma unroll
  for (int nf=0;nf<4;++nf)
    #pragma unroll
    for (int r=0;r<4;++r)
      Dt2[wave*16 + lg*4 + r][nf*16 + lr] = f2b(acc[nf][r]);
  __syncthreads();
  #pragma unroll
  for (int it=0; it<2; ++it){
    int e = it*256 + tid;
    int row = e >> 3, seg = e & 7;
    uint4 v = *reinterpret_cast<uint4*>(&Dt2[row][seg*8]);
    *reinterpret_cast<uint4*>(&P3[(((size_t)nt*4 + (seg>>1))*4096 + j0 + row)*16 + (seg&1)*8]) = v;
  }
}

// ---------- xpre[nt][j] = xb @ Wx ----------
__global__ void k_xmm(const ushort_t* __restrict__ WcatT, const ushort_t* __restrict__ xb,
                      ushort_t* __restrict__ xpre) {
  __shared__ ushort_t As[64*64];
  __shared__ ushort_t Bs[64*64];
  __shared__ float Dt[64][68];
  int jt = blockIdx.x, mt = blockIdx.y;
  int j0 = jt*64, m0 = mt*64;
  int tid = threadIdx.x;
  int wave = tid>>6, lane = tid&63, lr = lane&15, lg = lane>>4;
  int srow = lane>>3, sxor8 = ((lane&7)^srow)*8;
  f32x4 acc[4];
  #pragma unroll
  for (int nf=0;nf<4;++nf) acc[nf] = (f32x4){0.f,0.f,0.f,0.f};
  for (int kc = 0; kc < 512; kc += 64){
    __syncthreads();
    #pragma unroll
    for (int u = 0; u < 2; ++u){
      int r0 = wave*16 + u*8;
      const ushort_t* srcA = &WcatT[(size_t)(j0 + r0 + srow)*2560 + kc + sxor8];
      const ushort_t* srcB = &xb[(size_t)(m0 + r0 + srow)*512 + kc + sxor8];
      __builtin_amdgcn_global_load_lds((gvoid_t*)srcA, (lvoid_t*)&As[r0*64], 16, 0, 0);
      __builtin_amdgcn_global_load_lds((gvoid_t*)srcB, (lvoid_t*)&Bs[r0*64], 16, 0, 0);
    }
    __syncthreads();
    #pragma unroll
    for (int kk = 0; kk < 2; ++kk){
      int swz = (((kk*4 + lg) ^ (lr & 7)) * 8);
      short8 af = *reinterpret_cast<short8*>(&As[(wave*16 + lr)*64 + swz]);
      #pragma unroll
      for (int nf = 0; nf < 4; ++nf){
        short8 bf = *reinterpret_cast<short8*>(&Bs[(nf*16 + lr)*64 + swz]);
        acc[nf] = __builtin_amdgcn_mfma_f32_16x16x32_bf16(af, bf, acc[nf], 0, 0, 0);
      }
    }
  }
  __syncthreads();
  #pragma unroll
  for (int nf=0; nf<4; ++nf)
    #pragma unroll
    for (int r=0;r<4;++r)
      Dt[nf*16+lr][wave*16 + lg*4 + r] = acc[nf][r];
  __syncthreads();
  #pragma unroll
  for (int it=0; it<4; ++it){
    int e = tid + it*256;
    int nrow = e >> 4, seg = e & 15;
    float4 v = *reinterpret_cast<float4*>(&Dt[nrow][seg*4]);
    ushort4 o; o.x=f2b(v.x); o.y=f2b(v.y); o.z=f2b(v.z); o.w=f2b(v.w);
    *reinterpret_cast<ushort4*>(&xpre[(size_t)(m0+nrow)*4096 + j0 + seg*4]) = o;
  }
}

// ---------- per-step gates + c/h update + score partials (256 blocks) ----------
__global__ void k_gate(int i, const ushort_t* __restrict__ xpre, const ushort_t* __restrict__ a_part,
                       const float* __restrict__ bvec, const ushort_t* __restrict__ P3,
                       const float* __restrict__ A_flat, const float* __restrict__ hbuf,
                       float* __restrict__ cbuf, const float* __restrict__ sp_rd,
                       float* __restrict__ sp_wr, ushort_t* __restrict__ hbf,
                       ushort_t* __restrict__ hall) {
  __shared__ float wvLds[16];
  __shared__ float wred[4][16];
  int n = blockIdx.x >> 2, sp = blockIdx.x & 3;
  int tid = threadIdx.x;
  int wave = tid>>6, lane = tid&63;
  int k = sp*256 + tid;
  float hv;
  if (i == 0){
    hv = hbuf[n*1024 + k];
    cbuf[n*1024 + k] = hv;
    hbf[n*1024 + k] = f2b(hv);
  } else {
    if (tid < 16){
      float sv = (sp_rd[(n*4+0)*16+tid] + sp_rd[(n*4+1)*16+tid] +
                  sp_rd[(n*4+2)*16+tid] + sp_rd[(n*4+3)*16+tid]) * (1.f/32.f);
      float m = sv;
      #pragma unroll
      for (int d=1; d<16; d<<=1) m = fmaxf(m, __shfl_xor(m, d, 64));
      float e = __expf(sv - m);
      float s = e;
      #pragma unroll
      for (int d=1; d<16; d<<=1) s += __shfl_xor(s, d, 64);
      wvLds[tid] = e / s;
    }
    __syncthreads();
    float wv[16];
    #pragma unroll
    for (int p=0;p<16;++p) wv[p] = wvLds[p];
    float av[4];
    #pragma unroll
    for (int g=0;g<4;++g){
      int j = g*1024 + k;
      float x = bvec[j] + b2f(xpre[(size_t)(n*32 + (i-1))*4096 + j]);
      #pragma unroll
      for (int ks=0;ks<8;++ks) x += b2f(a_part[((size_t)ks*64 + n)*4096 + j]);
      const ushort_t* pp = &P3[((size_t)n*4096 + j)*16];
      short8 p0 = *reinterpret_cast<const short8*>(pp);
      short8 p1 = *reinterpret_cast<const short8*>(pp+8);
      #pragma unroll
      for (int p=0;p<8;++p) x += wv[p]*b2f((ushort_t)p0[p]);
      #pragma unroll
      for (int p=0;p<8;++p) x += wv[8+p]*b2f((ushort_t)p1[p]);
      av[g]=x;
    }
    float ig=sigmoidf_(av[0]), fg=sigmoidf_(av[1]), og=sigmoidf_(av[2]), gg=tanhf(av[3]);
    float c = fg*cbuf[n*1024+k] + ig*gg;
    hv = og*tanhf(c);
    cbuf[n*1024+k] = c;
    hall[((size_t)n*32 + (i-1))*1024 + k] = f2b(hv);
    if (i < 32) hbf[n*1024+k] = f2b(hv);
  }
  if (i == 32) return;
  float sacc[16];
  const float* An = &A_flat[((size_t)n*1024 + k)*16];
  #pragma unroll
  for (int p=0;p<16;p+=4){
    float4 a4 = *reinterpret_cast<const float4*>(&An[p]);
    sacc[p] = hv*a4.x; sacc[p+1] = hv*a4.y; sacc[p+2] = hv*a4.z; sacc[p+3] = hv*a4.w;
  }
  #pragma unroll
  for (int d=1; d<64; d<<=1)
    #pragma unroll
    for (int p=0;p<16;++p) sacc[p] += __shfl_xor(sacc[p], d, 64);
  if (lane == 0)
    #pragma unroll
    for (int p=0;p<16;++p) wred[wave][p] = sacc[p];
  __syncthreads();
  if (tid < 16)
    sp_wr[(n*4+sp)*16 + tid] = wred[0][tid]+wred[1][tid]+wred[2][tid]+wred[3][tid];
}

// ---------- a_part[ks] = h @ Wh (K-chunk ks of 128; 512 blocks; bf16 out) ----------
__global__ void k_mm(const ushort_t* __restrict__ WcatT, const ushort_t* __restrict__ hbf,
                     ushort_t* __restrict__ a_part) {
  __shared__ ushort_t As[64*64];
  __shared__ ushort_t Bs[64*64];
  __shared__ float Dt[64][68];
  int jt = blockIdx.x, ks = blockIdx.y;
  int j0 = jt*64;
  int tid = threadIdx.x;
  int wave = tid>>6, lane = tid&63, lr = lane&15, lg = lane>>4;
  int srow = lane>>3, sxor8 = ((lane&7)^srow)*8;
  f32x4 acc[4];
  #pragma unroll
  for (int nf=0;nf<4;++nf) acc[nf] = (f32x4){0.f,0.f,0.f,0.f};
  for (int kc = 0; kc < 128; kc += 64){
    __syncthreads();
    #pragma unroll
    for (int u = 0; u < 2; ++u){
      int r0 = wave*16 + u*8;
      const ushort_t* srcA = &WcatT[(size_t)(j0 + r0 + srow)*2560 + 512 + ks*128 + kc + sxor8];
      const ushort_t* srcB = &hbf[(size_t)(r0 + srow)*1024 + ks*128 + kc + sxor8];
      __builtin_amdgcn_global_load_lds((gvoid_t*)srcA, (lvoid_t*)&As[r0*64], 16, 0, 0);
      __builtin_amdgcn_global_load_lds((gvoid_t*)srcB, (lvoid_t*)&Bs[r0*64], 16, 0, 0);
    }
    __syncthreads();
    #pragma unroll
    for (int kk = 0; kk < 2; ++kk){
      int swz = (((kk*4 + lg) ^ (lr & 7)) * 8);
      short8 af = *reinterpret_cast<short8*>(&As[(wave*16 + lr)*64 + swz]);
      #pragma unroll
      for (int nf = 0; nf < 4; ++nf){
        short8 bf = *reinterpret_cast<short8*>(&Bs[(nf*16 + lr)*64 + swz]);
        acc[nf] = __builtin_amdgcn_mfma_f32_16x16x32_bf16(af, bf, acc[nf], 0, 0, 0);
      }
    }
  }
  __syncthreads();
  #pragma unroll
  for (int nf=0; nf<4; ++nf)
    #pragma unroll
    for (int r=0;r<4;++r)
      Dt[nf*16+lr][wave*16 + lg*4 + r] = acc[nf][r];
  __syncthreads();
  #pragma unroll
  for (int it=0; it<4; ++it){
    int e = tid + it*256;
    int nrow = e >> 4, seg = e & 15;
    float4 v = *reinterpret_cast<float4*>(&Dt[nrow][seg*4]);
    ushort4 o; o.x=f2b(v.x); o.y=f2b(v.y); o.z=f2b(v.z); o.w=f2b(v.w);
    *reinterpret_cast<ushort4*>(&a_part[((size_t)ks*64 + nrow)*4096 + j0 + seg*4]) = o;
  }
}

// ---------- scores: 256v x 256r tile, 2-phase barriers, 8 waves, fused partial lse ----------
__global__ void __launch_bounds__(512, 2)
k_score(const ushort_t* __restrict__ WoutT, const ushort_t* __restrict__ hall,
        const float* __restrict__ b_out,
        float* __restrict__ pmax, float* __restrict__ psum) {
  __shared__ ushort_t A_lds[256*64];
  __shared__ ushort_t B_lds[256*64];
  __shared__ float bLds[256];
  __shared__ float pmLds[2][256];
  __shared__ float psLds[2][256];

  int bid = blockIdx.x;
  int wg = (bid & 7) * 125 + (bid >> 3);   // 1000 = 8 x 125, bijective XCD swizzle
  int vb = wg >> 3, rb = wg & 7;
  size_t v0 = (size_t)vb * 256, r0 = (size_t)rb * 256;
  int tid = threadIdx.x;
  int wid = tid >> 6, lane = tid & 63;
  int wr = wid >> 2, wc = wid & 3;         // wave: v-half (128 rows), r-quarter (64 cols)
  int lr = lane & 15, lg = lane >> 4;
  int srow = lane >> 3, sxor8 = ((lane & 7) ^ srow) * 8;

  if (tid < 256) bLds[tid] = b_out[v0 + tid];

  const ushort_t* Abase = WoutT + v0*1024 + (size_t)srow*1024 + sxor8;
  const ushort_t* Bbase = hall  + r0*1024 + (size_t)srow*1024 + sxor8;

  f32x4 acc[8][4];
  #pragma unroll
  for (int fi=0; fi<8; ++fi)
    #pragma unroll
    for (int fj=0; fj<4; ++fj) acc[fi][fj] = (f32x4){0.f,0.f,0.f,0.f};

  for (int kc = 0; kc < 1024; kc += 64) {
    __syncthreads();   // previous tile's ds_reads complete
    #pragma unroll
    for (int u = 0; u < 4; ++u)
      __builtin_amdgcn_global_load_lds(
        (gvoid_t*)(Abase + (size_t)(u*64 + wid*8)*1024 + kc),
        (lvoid_t*)&A_lds[(u*64 + wid*8)*64], 16, 0, 0);
    #pragma unroll
    for (int u = 0; u < 4; ++u)
      __builtin_amdgcn_global_load_lds(
        (gvoid_t*)(Bbase + (size_t)(u*64 + wid*8)*1024 + kc),
        (lvoid_t*)&B_lds[(u*64 + wid*8)*64], 16, 0, 0);
    __syncthreads();   // vmcnt(0) drain: tile ready
    #pragma unroll
    for (int kk = 0; kk < 2; ++kk) {
      int swz = ((kk*4 + lg) ^ (lr & 7)) << 3;
      short8 bf0 = *reinterpret_cast<short8*>(&B_lds[(wc*64 +      lr)*64 + swz]);
      short8 bf1 = *reinterpret_cast<short8*>(&B_lds[(wc*64 + 16 + lr)*64 + swz]);
      short8 bf2 = *reinterpret_cast<short8*>(&B_lds[(wc*64 + 32 + lr)*64 + swz]);
      short8 bf3 = *reinterpret_cast<short8*>(&B_lds[(wc*64 + 48 + lr)*64 + swz]);
      #pragma unroll
      for (int fi = 0; fi < 8; ++fi) {
        short8 af = *reinterpret_cast<short8*>(&A_lds[(wr*128 + fi*16 + lr)*64 + swz]);
        acc[fi][0] = __builtin_amdgcn_mfma_f32_16x16x32_bf16(af, bf0, acc[fi][0], 0,0,0);
        acc[fi][1] = __builtin_amdgcn_mfma_f32_16x16x32_bf16(af, bf1, acc[fi][1], 0,0,0);
        acc[fi][2] = __builtin_amdgcn_mfma_f32_16x16x32_bf16(af, bf2, acc[fi][2], 0,0,0);
        acc[fi][3] = __builtin_amdgcn_mfma_f32_16x16x32_bf16(af, bf3, acc[fi][3], 0,0,0);
      }
    }
  }

  // ---- epilogue: bias + partial logsumexp over the 256-v tile ----
  __syncthreads();
  #pragma unroll
  for (int fj=0; fj<4; ++fj){
    float m = -1e30f;
    #pragma unroll
    for (int fi=0; fi<8; ++fi)
      #pragma unroll
      for (int rr=0; rr<4; ++rr){
        float x = acc[fi][fj][rr] + bLds[wr*128 + fi*16 + lg*4 + rr];
        m = fmaxf(m, x);
      }
    float ssum = 0.f;
    #pragma unroll
    for (int fi=0; fi<8; ++fi)
      #pragma unroll
      for (int rr=0; rr<4; ++rr){
        float x = acc[fi][fj][rr] + bLds[wr*128 + fi*16 + lg*4 + rr];
        ssum += __expf(x - m);
      }
    #pragma unroll
    for (int d=16; d<=32; d<<=1){
      float om = __shfl_xor(m, d, 64);
      float os = __shfl_xor(ssum, d, 64);
      float nm = fmaxf(m, om);
      ssum = ssum*__expf(m-nm) + os*__expf(om-nm);
      m = nm;
    }
    if (lg == 0){
      pmLds[wr][wc*64 + fj*16 + lr] = m;
      psLds[wr][wc*64 + fj*16 + lr] = ssum;
    }
  }
  __syncthreads();
  if (tid < 256){
    float m0 = pmLds[0][tid], m1 = pmLds[1][tid];
    float m = fmaxf(m0, m1);
    float sv = psLds[0][tid]*__expf(m0-m) + psLds[1][tid]*__expf(m1-m);
    pmax[(size_t)(r0 + tid)*VTILES + vb] = m;
    psum[(size_t)(r0 + tid)*VTILES + vb] = sv;
  }
}

// ---------- target score + lse combine -> per-row masked nll ----------
__global__ void k_nll(const ushort_t* __restrict__ hall, const ushort_t* __restrict__ WoutT,
                      const float* __restrict__ b_out, const int* __restrict__ captions,
                      const float* __restrict__ pmax, const float* __restrict__ psum,
                      float* __restrict__ row_loss) {
  int tid = threadIdx.x;
  int wave = tid>>6, lane = tid&63;
  int r = blockIdx.x*4 + wave;
  int n = r>>5, t = r&31;
  int y = captions[n*33 + t + 1];
  const ushort_t* hrow = hall + (size_t)r*1024;
  const ushort_t* wrow = WoutT + (size_t)y*1024;
  float dot = 0.f;
  #pragma unroll
  for (int i=0;i<2;++i){
    int off = lane*8 + i*512;
    short8 hv = *reinterpret_cast<const short8*>(&hrow[off]);
    short8 wv = *reinterpret_cast<const short8*>(&wrow[off]);
    #pragma unroll
    for (int e2=0;e2<8;++e2) dot += b2f((ushort_t)hv[e2])*b2f((ushort_t)wv[e2]);
  }
  float m = -1e30f, s = 0.f;
  for (int j = lane; j < VTILES; j += 64){
    float mj = pmax[(size_t)r*VTILES + j];
    float sj = psum[(size_t)r*VTILES + j];
    float nm = fmaxf(m, mj);
    s = s*__expf(m-nm) + sj*__expf(mj-nm);
    m = nm;
  }
  #pragma unroll
  for (int d=32; d>=1; d>>=1){
    dot += __shfl_xor(dot, d, 64);
    float om = __shfl_xor(m, d, 64);
    float os = __shfl_xor(s, d, 64);
    float nm = fmaxf(m, om);
    s = s*__expf(m-nm) + os*__expf(om-nm);
    m = nm;
  }
  if (lane==0){
    float lse = m + __logf(s);
    row_loss[r] = (y != 0) ? (lse - (dot + b_out[y])) : 0.f;
  }
}

// ---------- final deterministic sum ----------
__global__ void k_final(const float* __restrict__ row_loss, float* __restrict__ out) {
  __shared__ float red[256];
  int tid = threadIdx.x;
  float s = 0.f;
  #pragma unroll
  for (int i=0;i<8;++i) s += row_loss[tid + i*256];
  red[tid] = s;
  __syncthreads();
  for (int off=128; off>=1; off>>=1){
    if (tid<off) red[tid] += red[tid+off];
    __syncthreads();
  }
  if (tid==0) out[0] = red[0] * (1.f/64.f);
}

extern "C" void kernel_launch(void* const* d_in, const int* in_sizes, int n_in,
                              void* d_out, int out_size, void* d_ws, size_t ws_size,
                              hipStream_t stream) {
  const float* features = (const float*)d_in[0];
  const int*   captions = (const int*)d_in[1];
  const float* W_embed  = (const float*)d_in[2];
  const float* Wx       = (const float*)d_in[3];
  const float* Wh       = (const float*)d_in[4];
  const float* Wattn    = (const float*)d_in[5];
  const float* b        = (const float*)d_in[6];
  const float* W_proj   = (const float*)d_in[7];
  const float* b_proj   = (const float*)d_in[8];
  const float* W_out    = (const float*)d_in[9];
  const float* b_out    = (const float*)d_in[10];
  float* out = (float*)d_out;

  char* wsp = (char*)d_ws;
  size_t off = 0;
  auto alloc = [&](size_t bytes)->char*{
    char* p = wsp + off; off += (bytes + 255) & ~(size_t)255; return p;
  };
  ushort_t* WcatT  = (ushort_t*)alloc((size_t)4096*2560*2);
  ushort_t* WoutT  = (ushort_t*)alloc((size_t)32000*1024*2);
  ushort_t* WprojT = (ushort_t*)alloc((size_t)1024*1024*2);
  ushort_t* fBT    = (ushort_t*)alloc((size_t)1024*1024*2);
  ushort_t* Abt    = (ushort_t*)alloc((size_t)1024*1024*2);
  float* A_flat    = (float*)alloc((size_t)64*1024*16*4);
  ushort_t* xb     = (ushort_t*)alloc((size_t)64*32*512*2);
  float* hbuf      = (float*)alloc((size_t)64*1024*4);
  ushort_t* P3     = (ushort_t*)alloc((size_t)64*4096*16*2);
  ushort_t* xpre   = (ushort_t*)alloc((size_t)2048*4096*2);
  ushort_t* a_part = (ushort_t*)alloc((size_t)8*64*4096*2);
  ushort_t* hbf    = (ushort_t*)alloc((size_t)64*1024*2);
  float* cbuf      = (float*)alloc((size_t)64*1024*4);
  float* spbuf     = (float*)alloc((size_t)2*64*4*16*4);
  ushort_t* hall   = (ushort_t*)alloc((size_t)2048*1024*2);
  float* pmax      = (float*)alloc((size_t)2048*VTILES*4);
  float* psum      = (float*)alloc((size_t)2048*VTILES*4);
  float* row_loss  = (float*)alloc((size_t)2048*4);

  hipLaunchKernelGGL(k_transpose_cvt, dim3(64, 8),   dim3(256), 0, stream, Wx,     WcatT,  4096, 2560, 0);
  hipLaunchKernelGGL(k_transpose_cvt, dim3(64, 16),  dim3(256), 0, stream, Wh,     WcatT,  4096, 2560, 512);
  hipLaunchKernelGGL(k_transpose_cvt, dim3(64, 16),  dim3(256), 0, stream, Wattn,  WcatT,  4096, 2560, 1536);
  hipLaunchKernelGGL(k_transpose_cvt, dim3(500, 16), dim3(256), 0, stream, W_out,  WoutT,  32000, 1024, 0);
  hipLaunchKernelGGL(k_transpose_cvt, dim3(16, 16),  dim3(256), 0, stream, W_proj, WprojT, 1024, 1024, 0);
  hipLaunchKernelGGL(k_featT, dim3(64), dim3(256), 0, stream, features, fBT);
  hipLaunchKernelGGL(k_embed, dim3(1024), dim3(256), 0, stream, captions, W_embed, xb);
  hipLaunchKernelGGL(k_projmm, dim3(16, 16), dim3(256), 0, stream, WprojT, fBT, b_proj, A_flat, Abt, hbuf);
  hipLaunchKernelGGL(k_pmm, dim3(64, 16), dim3(256), 0, stream, WcatT, Abt, P3);
  hipLaunchKernelGGL(k_xmm, dim3(64, 32), dim3(256), 0, stream, WcatT, xb, xpre);

  for (int i = 0; i <= 32; ++i){
    const float* sp_rd = spbuf + ((i+1)&1)*4096;
    float*       sp_wr = spbuf + (i&1)*4096;
    hipLaunchKernelGGL(k_gate, dim3(256), dim3(256), 0, stream, i, xpre, a_part, b, P3,
                       A_flat, hbuf, cbuf, sp_rd, sp_wr, hbf, hall);
    if (i < 32)
      hipLaunchKernelGGL(k_mm, dim3(64, 8), dim3(256), 0, stream, WcatT, hbf, a_part);
  }

  hipLaunchKernelGGL(k_score, dim3(1000), dim3(512), 0, stream, WoutT, hall, b_out, pmax, psum);
  hipLaunchKernelGGL(k_nll, dim3(512), dim3(256), 0, stream, hall, WoutT, b_out, captions, pmax, psum, row_loss);
  hipLaunchKernelGGL(k_final, dim3(1), dim3(256), 0, stream, row_loss, out);
}

// Round 12
// 586.505 us; speedup vs baseline: 1.4349x; 1.0172x over previous
//
#include <hip/hip_runtime.h>
#include <hip/hip_bf16.h>
#include <math.h>

typedef __attribute__((ext_vector_type(8))) short short8;
typedef __attribute__((ext_vector_type(4))) float f32x4;
typedef unsigned short ushort_t;
typedef unsigned int uint_t;

typedef __attribute__((address_space(1))) const void gvoid_t;
typedef __attribute__((address_space(3))) void lvoid_t;

#define VTILES 125

static __device__ __forceinline__ ushort_t f2b(float f){
  __hip_bfloat16 h = __float2bfloat16(f);
  return *reinterpret_cast<ushort_t*>(&h);
}
static __device__ __forceinline__ float b2f(ushort_t u){
  __hip_bfloat16 h = *reinterpret_cast<__hip_bfloat16*>(&u);
  return __bfloat162float(h);
}
static __device__ __forceinline__ float sigmoidf_(float x){ return 1.0f/(1.0f+__expf(-x)); }

// ---------- transpose + f32->bf16 convert: dst[c][dcoloff + r] = src[r][c] ----------
__global__ void k_transpose_cvt(const float* __restrict__ src, ushort_t* __restrict__ dst,
                                int C, int dstride, int dcoloff) {
  __shared__ ushort_t tile[64][72];
  int cb = blockIdx.x * 64, rb = blockIdx.y * 64;
  int tid = threadIdx.x;
  for (int it = 0; it < 4; ++it) {
    int e = tid + it*256;
    int row = e >> 4;
    int seg = e & 15;
    float4 v = *reinterpret_cast<const float4*>(&src[(size_t)(rb+row)*C + cb + seg*4]);
    tile[seg*4+0][row] = f2b(v.x);
    tile[seg*4+1][row] = f2b(v.y);
    tile[seg*4+2][row] = f2b(v.z);
    tile[seg*4+3][row] = f2b(v.w);
  }
  __syncthreads();
  for (int it = 0; it < 2; ++it) {
    int e = tid + it*256;
    int cl = e >> 3;
    int seg = e & 7;
    uint4 v = *reinterpret_cast<uint4*>(&tile[cl][seg*8]);
    *reinterpret_cast<uint4*>(&dst[(size_t)(cb+cl)*dstride + dcoloff + rb + seg*8]) = v;
  }
}

// ---------- features [n][d][16] f32 -> fBT [(n*16+p)][d] bf16 ----------
__global__ void k_featT(const float* __restrict__ feat, ushort_t* __restrict__ fBT) {
  __shared__ ushort_t t[16][264];
  int n = blockIdx.x;
  int tid = threadIdx.x;
  for (int it = 0; it < 4; ++it) {
    int d = it*256 + tid;
    const float* src = &feat[((size_t)n*1024 + d)*16];
    #pragma unroll
    for (int q = 0; q < 4; ++q) {
      float4 v = *reinterpret_cast<const float4*>(&src[q*4]);
      t[q*4+0][tid] = f2b(v.x);
      t[q*4+1][tid] = f2b(v.y);
      t[q*4+2][tid] = f2b(v.z);
      t[q*4+3][tid] = f2b(v.w);
    }
    __syncthreads();
    #pragma unroll
    for (int w = 0; w < 2; ++w) {
      int e = tid + w*256;
      int p = e >> 5;
      int seg = e & 31;
      uint4 v = *reinterpret_cast<uint4*>(&t[p][seg*8]);
      *reinterpret_cast<uint4*>(&fBT[((size_t)n*16 + p)*1024 + it*256 + seg*8]) = v;
    }
    __syncthreads();
  }
}

// ---------- embedding gather -> bf16 ----------
__global__ void k_embed(const int* __restrict__ captions, const float* __restrict__ W_embed,
                        ushort_t* __restrict__ xb) {
  int e = (blockIdx.x*256 + threadIdx.x) * 4;
  int nt = e >> 9;
  int n = nt >> 5, t = nt & 31;
  int col = e & 511;
  int tok = captions[n*33 + t];
  float4 v = *reinterpret_cast<const float4*>(&W_embed[(size_t)tok*512 + col]);
  ushort4 o; o.x=f2b(v.x); o.y=f2b(v.y); o.z=f2b(v.z); o.w=f2b(v.w);
  *reinterpret_cast<ushort4*>(&xb[e]) = o;
}

// ---------- A_flat/Abt = WprojT @ fBT^T + b_proj ; h0 fused (MFMA GEMM) ----------
__global__ void k_projmm(const ushort_t* __restrict__ WprojT, const ushort_t* __restrict__ fBT,
                         const float* __restrict__ b_proj, float* __restrict__ A_flat,
                         ushort_t* __restrict__ Abt, float* __restrict__ hbuf) {
  __shared__ ushort_t As[64*64];
  __shared__ ushort_t Bs[64*64];
  int kt = blockIdx.x, nt = blockIdx.y;
  int k0 = kt*64, n0 = nt*64;
  int tid = threadIdx.x;
  int wave = tid>>6, lane = tid&63, lr = lane&15, lg = lane>>4;
  int srow = lane>>3, sxor8 = ((lane&7)^srow)*8;
  f32x4 acc[4];
  #pragma unroll
  for (int nf=0;nf<4;++nf) acc[nf] = (f32x4){0.f,0.f,0.f,0.f};
  for (int kc = 0; kc < 1024; kc += 64){
    __syncthreads();
    #pragma unroll
    for (int u = 0; u < 2; ++u){
      int r0 = wave*16 + u*8;
      const ushort_t* srcA = &WprojT[(size_t)(k0 + r0 + srow)*1024 + kc + sxor8];
      const ushort_t* srcB = &fBT[(size_t)(n0 + r0 + srow)*1024 + kc + sxor8];
      __builtin_amdgcn_global_load_lds((gvoid_t*)srcA, (lvoid_t*)&As[r0*64], 16, 0, 0);
      __builtin_amdgcn_global_load_lds((gvoid_t*)srcB, (lvoid_t*)&Bs[r0*64], 16, 0, 0);
    }
    __syncthreads();
    #pragma unroll
    for (int kk = 0; kk < 2; ++kk){
      int swz = (((kk*4 + lg) ^ (lr & 7)) * 8);
      short8 af = *reinterpret_cast<short8*>(&As[(wave*16 + lr)*64 + swz]);
      #pragma unroll
      for (int nf = 0; nf < 4; ++nf){
        short8 bf = *reinterpret_cast<short8*>(&Bs[(nf*16 + lr)*64 + swz]);
        acc[nf] = __builtin_amdgcn_mfma_f32_16x16x32_bf16(af, bf, acc[nf], 0, 0, 0);
      }
    }
  }
  #pragma unroll
  for (int nf=0;nf<4;++nf){
    int ncol = n0 + nf*16 + lr;
    int nidx = ncol >> 4, p = ncol & 15;
    ushort4 ab;
    #pragma unroll
    for (int r=0;r<4;++r){
      int kh = k0 + wave*16 + lg*4 + r;
      float val = acc[nf][r] + b_proj[kh];
      A_flat[((size_t)nidx*1024 + kh)*16 + p] = val;
      (&ab.x)[r] = f2b(val);
      float s = val;
      s += __shfl_xor(s, 1, 64);
      s += __shfl_xor(s, 2, 64);
      s += __shfl_xor(s, 4, 64);
      s += __shfl_xor(s, 8, 64);
      if (lr == 0) hbuf[(nt*4 + nf)*1024 + kh] = s * (1.f/16.f);
    }
    *reinterpret_cast<ushort4*>(&Abt[(size_t)ncol*1024 + k0 + wave*16 + lg*4]) = ab;
  }
}

// ---------- P3[n][j][p] = sum_k Wattn[k][j] * A_flat[n][k][p]  (MFMA GEMM) ----------
__global__ void k_pmm(const ushort_t* __restrict__ WcatT, const ushort_t* __restrict__ Abt,
                      ushort_t* __restrict__ P3) {
  __shared__ ushort_t As[64*64];
  __shared__ ushort_t Bs[64*64];
  __shared__ ushort_t Dt2[64][72];
  int jt = blockIdx.x, nt = blockIdx.y;
  int j0 = jt*64, n0 = nt*64;
  int tid = threadIdx.x;
  int wave = tid>>6, lane = tid&63, lr = lane&15, lg = lane>>4;
  int srow = lane>>3, sxor8 = ((lane&7)^srow)*8;
  f32x4 acc[4];
  #pragma unroll
  for (int nf=0;nf<4;++nf) acc[nf] = (f32x4){0.f,0.f,0.f,0.f};
  for (int kc = 0; kc < 1024; kc += 64){
    __syncthreads();
    #pragma unroll
    for (int u = 0; u < 2; ++u){
      int r0 = wave*16 + u*8;
      const ushort_t* srcA = &WcatT[(size_t)(j0 + r0 + srow)*2560 + 1536 + kc + sxor8];
      const ushort_t* srcB = &Abt[(size_t)(n0 + r0 + srow)*1024 + kc + sxor8];
      __builtin_amdgcn_global_load_lds((gvoid_t*)srcA, (lvoid_t*)&As[r0*64], 16, 0, 0);
      __builtin_amdgcn_global_load_lds((gvoid_t*)srcB, (lvoid_t*)&Bs[r0*64], 16, 0, 0);
    }
    __syncthreads();
    #pragma unroll
    for (int kk = 0; kk < 2; ++kk){
      int swz = (((kk*4 + lg) ^ (lr & 7)) * 8);
      short8 af = *reinterpret_cast<short8*>(&As[(wave*16 + lr)*64 + swz]);
      #pragma unroll
      for (int nf = 0; nf < 4; ++nf){
        short8 bf = *reinterpret_cast<short8*>(&Bs[(nf*16 + lr)*64 + swz]);
        acc[nf] = __builtin_amdgcn_mfma_f32_16x16x32_bf16(af, bf, acc[nf], 0, 0, 0);
      }
    }
  }
  __syncthreads();
  #pragma unroll
  for (int nf=0;nf<4;++nf)
    #pragma unroll
    for (int r=0;r<4;++r)
      Dt2[wave*16 + lg*4 + r][nf*16 + lr] = f2b(acc[nf][r]);
  __syncthreads();
  #pragma unroll
  for (int it=0; it<2; ++it){
    int e = it*256 + tid;
    int row = e >> 3, seg = e & 7;
    uint4 v = *reinterpret_cast<uint4*>(&Dt2[row][seg*8]);
    *reinterpret_cast<uint4*>(&P3[(((size_t)nt*4 + (seg>>1))*4096 + j0 + row)*16 + (seg&1)*8]) = v;
  }
}

// ---------- xpre[nt][j] = xb @ Wx ----------
__global__ void k_xmm(const ushort_t* __restrict__ WcatT, const ushort_t* __restrict__ xb,
                      ushort_t* __restrict__ xpre) {
  __shared__ ushort_t As[64*64];
  __shared__ ushort_t Bs[64*64];
  __shared__ float Dt[64][68];
  int jt = blockIdx.x, mt = blockIdx.y;
  int j0 = jt*64, m0 = mt*64;
  int tid = threadIdx.x;
  int wave = tid>>6, lane = tid&63, lr = lane&15, lg = lane>>4;
  int srow = lane>>3, sxor8 = ((lane&7)^srow)*8;
  f32x4 acc[4];
  #pragma unroll
  for (int nf=0;nf<4;++nf) acc[nf] = (f32x4){0.f,0.f,0.f,0.f};
  for (int kc = 0; kc < 512; kc += 64){
    __syncthreads();
    #pragma unroll
    for (int u = 0; u < 2; ++u){
      int r0 = wave*16 + u*8;
      const ushort_t* srcA = &WcatT[(size_t)(j0 + r0 + srow)*2560 + kc + sxor8];
      const ushort_t* srcB = &xb[(size_t)(m0 + r0 + srow)*512 + kc + sxor8];
      __builtin_amdgcn_global_load_lds((gvoid_t*)srcA, (lvoid_t*)&As[r0*64], 16, 0, 0);
      __builtin_amdgcn_global_load_lds((gvoid_t*)srcB, (lvoid_t*)&Bs[r0*64], 16, 0, 0);
    }
    __syncthreads();
    #pragma unroll
    for (int kk = 0; kk < 2; ++kk){
      int swz = (((kk*4 + lg) ^ (lr & 7)) * 8);
      short8 af = *reinterpret_cast<short8*>(&As[(wave*16 + lr)*64 + swz]);
      #pragma unroll
      for (int nf = 0; nf < 4; ++nf){
        short8 bf = *reinterpret_cast<short8*>(&Bs[(nf*16 + lr)*64 + swz]);
        acc[nf] = __builtin_amdgcn_mfma_f32_16x16x32_bf16(af, bf, acc[nf], 0, 0, 0);
      }
    }
  }
  __syncthreads();
  #pragma unroll
  for (int nf=0; nf<4; ++nf)
    #pragma unroll
    for (int r=0;r<4;++r)
      Dt[nf*16+lr][wave*16 + lg*4 + r] = acc[nf][r];
  __syncthreads();
  #pragma unroll
  for (int it=0; it<4; ++it){
    int e = tid + it*256;
    int nrow = e >> 4, seg = e & 15;
    float4 v = *reinterpret_cast<float4*>(&Dt[nrow][seg*4]);
    ushort4 o; o.x=f2b(v.x); o.y=f2b(v.y); o.z=f2b(v.z); o.w=f2b(v.w);
    *reinterpret_cast<ushort4*>(&xpre[(size_t)(m0+nrow)*4096 + j0 + seg*4]) = o;
  }
}

// ---------- per-step gates + c/h update + score partials (256 blocks) ----------
__global__ void k_gate(int i, const ushort_t* __restrict__ xpre, const ushort_t* __restrict__ a_part,
                       const float* __restrict__ bvec, const ushort_t* __restrict__ P3,
                       const float* __restrict__ A_flat, const float* __restrict__ hbuf,
                       float* __restrict__ cbuf, const float* __restrict__ sp_rd,
                       float* __restrict__ sp_wr, ushort_t* __restrict__ hbf,
                       ushort_t* __restrict__ hall) {
  __shared__ float wvLds[16];
  __shared__ float wred[4][16];
  int n = blockIdx.x >> 2, sp = blockIdx.x & 3;
  int tid = threadIdx.x;
  int wave = tid>>6, lane = tid&63;
  int k = sp*256 + tid;
  float hv;
  if (i == 0){
    hv = hbuf[n*1024 + k];
    cbuf[n*1024 + k] = hv;
    hbf[n*1024 + k] = f2b(hv);
  } else {
    if (tid < 16){
      float sv = (sp_rd[(n*4+0)*16+tid] + sp_rd[(n*4+1)*16+tid] +
                  sp_rd[(n*4+2)*16+tid] + sp_rd[(n*4+3)*16+tid]) * (1.f/32.f);
      float m = sv;
      #pragma unroll
      for (int d=1; d<16; d<<=1) m = fmaxf(m, __shfl_xor(m, d, 64));
      float e = __expf(sv - m);
      float s = e;
      #pragma unroll
      for (int d=1; d<16; d<<=1) s += __shfl_xor(s, d, 64);
      wvLds[tid] = e / s;
    }
    __syncthreads();
    float wv[16];
    #pragma unroll
    for (int p=0;p<16;++p) wv[p] = wvLds[p];
    float av[4];
    #pragma unroll
    for (int g=0;g<4;++g){
      int j = g*1024 + k;
      float x = bvec[j] + b2f(xpre[(size_t)(n*32 + (i-1))*4096 + j]);
      #pragma unroll
      for (int ks=0;ks<8;++ks) x += b2f(a_part[((size_t)ks*64 + n)*4096 + j]);
      const ushort_t* pp = &P3[((size_t)n*4096 + j)*16];
      short8 p0 = *reinterpret_cast<const short8*>(pp);
      short8 p1 = *reinterpret_cast<const short8*>(pp+8);
      #pragma unroll
      for (int p=0;p<8;++p) x += wv[p]*b2f((ushort_t)p0[p]);
      #pragma unroll
      for (int p=0;p<8;++p) x += wv[8+p]*b2f((ushort_t)p1[p]);
      av[g]=x;
    }
    float ig=sigmoidf_(av[0]), fg=sigmoidf_(av[1]), og=sigmoidf_(av[2]), gg=tanhf(av[3]);
    float c = fg*cbuf[n*1024+k] + ig*gg;
    hv = og*tanhf(c);
    cbuf[n*1024+k] = c;
    hall[((size_t)n*32 + (i-1))*1024 + k] = f2b(hv);
    if (i < 32) hbf[n*1024+k] = f2b(hv);
  }
  if (i == 32) return;
  float sacc[16];
  const float* An = &A_flat[((size_t)n*1024 + k)*16];
  #pragma unroll
  for (int p=0;p<16;p+=4){
    float4 a4 = *reinterpret_cast<const float4*>(&An[p]);
    sacc[p] = hv*a4.x; sacc[p+1] = hv*a4.y; sacc[p+2] = hv*a4.z; sacc[p+3] = hv*a4.w;
  }
  #pragma unroll
  for (int d=1; d<64; d<<=1)
    #pragma unroll
    for (int p=0;p<16;++p) sacc[p] += __shfl_xor(sacc[p], d, 64);
  if (lane == 0)
    #pragma unroll
    for (int p=0;p<16;++p) wred[wave][p] = sacc[p];
  __syncthreads();
  if (tid < 16)
    sp_wr[(n*4+sp)*16 + tid] = wred[0][tid]+wred[1][tid]+wred[2][tid]+wred[3][tid];
}

// ---------- a_part[ks] = h @ Wh (K-chunk ks of 128; 512 blocks; bf16 out) ----------
__global__ void k_mm(const ushort_t* __restrict__ WcatT, const ushort_t* __restrict__ hbf,
                     ushort_t* __restrict__ a_part) {
  __shared__ ushort_t As[64*64];
  __shared__ ushort_t Bs[64*64];
  __shared__ float Dt[64][68];
  int jt = blockIdx.x, ks = blockIdx.y;
  int j0 = jt*64;
  int tid = threadIdx.x;
  int wave = tid>>6, lane = tid&63, lr = lane&15, lg = lane>>4;
  int srow = lane>>3, sxor8 = ((lane&7)^srow)*8;
  f32x4 acc[4];
  #pragma unroll
  for (int nf=0;nf<4;++nf) acc[nf] = (f32x4){0.f,0.f,0.f,0.f};
  for (int kc = 0; kc < 128; kc += 64){
    __syncthreads();
    #pragma unroll
    for (int u = 0; u < 2; ++u){
      int r0 = wave*16 + u*8;
      const ushort_t* srcA = &WcatT[(size_t)(j0 + r0 + srow)*2560 + 512 + ks*128 + kc + sxor8];
      const ushort_t* srcB = &hbf[(size_t)(r0 + srow)*1024 + ks*128 + kc + sxor8];
      __builtin_amdgcn_global_load_lds((gvoid_t*)srcA, (lvoid_t*)&As[r0*64], 16, 0, 0);
      __builtin_amdgcn_global_load_lds((gvoid_t*)srcB, (lvoid_t*)&Bs[r0*64], 16, 0, 0);
    }
    __syncthreads();
    #pragma unroll
    for (int kk = 0; kk < 2; ++kk){
      int swz = (((kk*4 + lg) ^ (lr & 7)) * 8);
      short8 af = *reinterpret_cast<short8*>(&As[(wave*16 + lr)*64 + swz]);
      #pragma unroll
      for (int nf = 0; nf < 4; ++nf){
        short8 bf = *reinterpret_cast<short8*>(&Bs[(nf*16 + lr)*64 + swz]);
        acc[nf] = __builtin_amdgcn_mfma_f32_16x16x32_bf16(af, bf, acc[nf], 0, 0, 0);
      }
    }
  }
  __syncthreads();
  #pragma unroll
  for (int nf=0; nf<4; ++nf)
    #pragma unroll
    for (int r=0;r<4;++r)
      Dt[nf*16+lr][wave*16 + lg*4 + r] = acc[nf][r];
  __syncthreads();
  #pragma unroll
  for (int it=0; it<4; ++it){
    int e = tid + it*256;
    int nrow = e >> 4, seg = e & 15;
    float4 v = *reinterpret_cast<float4*>(&Dt[nrow][seg*4]);
    ushort4 o; o.x=f2b(v.x); o.y=f2b(v.y); o.z=f2b(v.z); o.w=f2b(v.w);
    *reinterpret_cast<ushort4*>(&a_part[((size_t)ks*64 + nrow)*4096 + j0 + seg*4]) = o;
  }
}

// ---------- scores: 256v x 128r tile, 2-phase barriers, 8 waves, fused partial lse ----------
__global__ void __launch_bounds__(512, 4)
k_score(const ushort_t* __restrict__ WoutT, const ushort_t* __restrict__ hall,
        const float* __restrict__ b_out,
        float* __restrict__ pmax, float* __restrict__ psum) {
  __shared__ ushort_t A_lds[256*64];
  __shared__ ushort_t B_lds[128*64];
  __shared__ float bLds[256];
  __shared__ float pmLds[2][128];
  __shared__ float psLds[2][128];

  int bid = blockIdx.x;
  int wg = (bid & 7) * 250 + (bid >> 3);   // 2000 = 8 x 250, bijective XCD swizzle
  int vb = wg >> 4, rb = wg & 15;
  size_t v0 = (size_t)vb * 256, r0 = (size_t)rb * 128;
  int tid = threadIdx.x;
  int wid = tid >> 6, lane = tid & 63;
  int wr = wid >> 2, wc = wid & 3;         // wave covers v-rows [wr*128,+128), r-cols [wc*32,+32)
  int lr = lane & 15, lg = lane >> 4;
  int srow = lane >> 3, sxor8 = ((lane & 7) ^ srow) * 8;

  if (tid < 256) bLds[tid] = b_out[v0 + tid];

  const ushort_t* Abase = WoutT + v0*1024 + (size_t)srow*1024 + sxor8;
  const ushort_t* Bbase = hall  + r0*1024 + (size_t)srow*1024 + sxor8;

  f32x4 acc[8][2];
  #pragma unroll
  for (int fi=0; fi<8; ++fi)
    #pragma unroll
    for (int fj=0; fj<2; ++fj) acc[fi][fj] = (f32x4){0.f,0.f,0.f,0.f};

  for (int kc = 0; kc < 1024; kc += 64) {
    __syncthreads();   // previous tile's ds_reads complete
    #pragma unroll
    for (int u = 0; u < 4; ++u)
      __builtin_amdgcn_global_load_lds(
        (gvoid_t*)(Abase + (size_t)(u*64 + wid*8)*1024 + kc),
        (lvoid_t*)&A_lds[(u*64 + wid*8)*64], 16, 0, 0);
    #pragma unroll
    for (int u = 0; u < 2; ++u)
      __builtin_amdgcn_global_load_lds(
        (gvoid_t*)(Bbase + (size_t)(u*64 + wid*8)*1024 + kc),
        (lvoid_t*)&B_lds[(u*64 + wid*8)*64], 16, 0, 0);
    __syncthreads();   // vmcnt(0) drain: tile ready
    #pragma unroll
    for (int kk = 0; kk < 2; ++kk) {
      int swz = ((kk*4 + lg) ^ (lr & 7)) << 3;
      short8 bf0 = *reinterpret_cast<short8*>(&B_lds[(wc*32 + lr)*64 + swz]);
      short8 bf1 = *reinterpret_cast<short8*>(&B_lds[(wc*32 + 16 + lr)*64 + swz]);
      #pragma unroll
      for (int fi = 0; fi < 8; ++fi) {
        short8 af = *reinterpret_cast<short8*>(&A_lds[(wr*128 + fi*16 + lr)*64 + swz]);
        acc[fi][0] = __builtin_amdgcn_mfma_f32_16x16x32_bf16(af, bf0, acc[fi][0], 0,0,0);
        acc[fi][1] = __builtin_amdgcn_mfma_f32_16x16x32_bf16(af, bf1, acc[fi][1], 0,0,0);
      }
    }
  }

  __syncthreads();
  float pm_[2], ps_[2];
  #pragma unroll
  for (int fj=0; fj<2; ++fj){
    float m = -1e30f;
    #pragma unroll
    for (int fi=0; fi<8; ++fi)
      #pragma unroll
      for (int rr=0; rr<4; ++rr){
        float x = acc[fi][fj][rr] + bLds[wr*128 + fi*16 + lg*4 + rr];
        m = fmaxf(m, x);
      }
    float ssum = 0.f;
    #pragma unroll
    for (int fi=0; fi<8; ++fi)
      #pragma unroll
      for (int rr=0; rr<4; ++rr){
        float x = acc[fi][fj][rr] + bLds[wr*128 + fi*16 + lg*4 + rr];
        ssum += __expf(x - m);
      }
    #pragma unroll
    for (int d=16; d<=32; d<<=1){
      float om = __shfl_xor(m, d, 64);
      float os = __shfl_xor(ssum, d, 64);
      float nm = fmaxf(m, om);
      ssum = ssum*__expf(m-nm) + os*__expf(om-nm);
      m = nm;
    }
    pm_[fj] = m; ps_[fj] = ssum;
  }
  if (lg == 0){
    #pragma unroll
    for (int fj=0; fj<2; ++fj){
      pmLds[wr][wc*32 + fj*16 + lr] = pm_[fj];
      psLds[wr][wc*32 + fj*16 + lr] = ps_[fj];
    }
  }
  __syncthreads();
  if (tid < 128){
    float m0 = pmLds[0][tid], m1 = pmLds[1][tid];
    float m = fmaxf(m0, m1);
    float sv = psLds[0][tid]*__expf(m0-m) + psLds[1][tid]*__expf(m1-m);
    pmax[(size_t)(r0 + tid)*VTILES + vb] = m;
    psum[(size_t)(r0 + tid)*VTILES + vb] = sv;
  }
}

// ---------- target score + lse combine -> per-row masked nll ----------
__global__ void k_nll(const ushort_t* __restrict__ hall, const ushort_t* __restrict__ WoutT,
                      const float* __restrict__ b_out, const int* __restrict__ captions,
                      const float* __restrict__ pmax, const float* __restrict__ psum,
                      float* __restrict__ row_loss) {
  int tid = threadIdx.x;
  int wave = tid>>6, lane = tid&63;
  int r = blockIdx.x*4 + wave;
  int n = r>>5, t = r&31;
  int y = captions[n*33 + t + 1];
  const ushort_t* hrow = hall + (size_t)r*1024;
  const ushort_t* wrow = WoutT + (size_t)y*1024;
  float dot = 0.f;
  #pragma unroll
  for (int i=0;i<2;++i){
    int off = lane*8 + i*512;
    short8 hv = *reinterpret_cast<const short8*>(&hrow[off]);
    short8 wv = *reinterpret_cast<const short8*>(&wrow[off]);
    #pragma unroll
    for (int e2=0;e2<8;++e2) dot += b2f((ushort_t)hv[e2])*b2f((ushort_t)wv[e2]);
  }
  float m = -1e30f, s = 0.f;
  for (int j = lane; j < VTILES; j += 64){
    float mj = pmax[(size_t)r*VTILES + j];
    float sj = psum[(size_t)r*VTILES + j];
    float nm = fmaxf(m, mj);
    s = s*__expf(m-nm) + sj*__expf(mj-nm);
    m = nm;
  }
  #pragma unroll
  for (int d=32; d>=1; d>>=1){
    dot += __shfl_xor(dot, d, 64);
    float om = __shfl_xor(m, d, 64);
    float os = __shfl_xor(s, d, 64);
    float nm = fmaxf(m, om);
    s = s*__expf(m-nm) + os*__expf(om-nm);
    m = nm;
  }
  if (lane==0){
    float lse = m + __logf(s);
    row_loss[r] = (y != 0) ? (lse - (dot + b_out[y])) : 0.f;
  }
}

// ---------- final deterministic sum ----------
__global__ void k_final(const float* __restrict__ row_loss, float* __restrict__ out) {
  __shared__ float red[256];
  int tid = threadIdx.x;
  float s = 0.f;
  #pragma unroll
  for (int i=0;i<8;++i) s += row_loss[tid + i*256];
  red[tid] = s;
  __syncthreads();
  for (int off=128; off>=1; off>>=1){
    if (tid<off) red[tid] += red[tid+off];
    __syncthreads();
  }
  if (tid==0) out[0] = red[0] * (1.f/64.f);
}

extern "C" void kernel_launch(void* const* d_in, const int* in_sizes, int n_in,
                              void* d_out, int out_size, void* d_ws, size_t ws_size,
                              hipStream_t stream) {
  const float* features = (const float*)d_in[0];
  const int*   captions = (const int*)d_in[1];
  const float* W_embed  = (const float*)d_in[2];
  const float* Wx       = (const float*)d_in[3];
  const float* Wh       = (const float*)d_in[4];
  const float* Wattn    = (const float*)d_in[5];
  const float* b        = (const float*)d_in[6];
  const float* W_proj   = (const float*)d_in[7];
  const float* b_proj   = (const float*)d_in[8];
  const float* W_out    = (const float*)d_in[9];
  const float* b_out    = (const float*)d_in[10];
  float* out = (float*)d_out;

  char* wsp = (char*)d_ws;
  size_t off = 0;
  auto alloc = [&](size_t bytes)->char*{
    char* p = wsp + off; off += (bytes + 255) & ~(size_t)255; return p;
  };
  ushort_t* WcatT  = (ushort_t*)alloc((size_t)4096*2560*2);
  ushort_t* WoutT  = (ushort_t*)alloc((size_t)32000*1024*2);
  ushort_t* WprojT = (ushort_t*)alloc((size_t)1024*1024*2);
  ushort_t* fBT    = (ushort_t*)alloc((size_t)1024*1024*2);
  ushort_t* Abt    = (ushort_t*)alloc((size_t)1024*1024*2);
  float* A_flat    = (float*)alloc((size_t)64*1024*16*4);
  ushort_t* xb     = (ushort_t*)alloc((size_t)64*32*512*2);
  float* hbuf      = (float*)alloc((size_t)64*1024*4);
  ushort_t* P3     = (ushort_t*)alloc((size_t)64*4096*16*2);
  ushort_t* xpre   = (ushort_t*)alloc((size_t)2048*4096*2);
  ushort_t* a_part = (ushort_t*)alloc((size_t)8*64*4096*2);
  ushort_t* hbf    = (ushort_t*)alloc((size_t)64*1024*2);
  float* cbuf      = (float*)alloc((size_t)64*1024*4);
  float* spbuf     = (float*)alloc((size_t)2*64*4*16*4);
  ushort_t* hall   = (ushort_t*)alloc((size_t)2048*1024*2);
  float* pmax      = (float*)alloc((size_t)2048*VTILES*4);
  float* psum      = (float*)alloc((size_t)2048*VTILES*4);
  float* row_loss  = (float*)alloc((size_t)2048*4);

  hipLaunchKernelGGL(k_transpose_cvt, dim3(64, 8),   dim3(256), 0, stream, Wx,     WcatT,  4096, 2560, 0);
  hipLaunchKernelGGL(k_transpose_cvt, dim3(64, 16),  dim3(256), 0, stream, Wh,     WcatT,  4096, 2560, 512);
  hipLaunchKernelGGL(k_transpose_cvt, dim3(64, 16),  dim3(256), 0, stream, Wattn,  WcatT,  4096, 2560, 1536);
  hipLaunchKernelGGL(k_transpose_cvt, dim3(500, 16), dim3(256), 0, stream, W_out,  WoutT,  32000, 1024, 0);
  hipLaunchKernelGGL(k_transpose_cvt, dim3(16, 16),  dim3(256), 0, stream, W_proj, WprojT, 1024, 1024, 0);
  hipLaunchKernelGGL(k_featT, dim3(64), dim3(256), 0, stream, features, fBT);
  hipLaunchKernelGGL(k_embed, dim3(1024), dim3(256), 0, stream, captions, W_embed, xb);
  hipLaunchKernelGGL(k_projmm, dim3(16, 16), dim3(256), 0, stream, WprojT, fBT, b_proj, A_flat, Abt, hbuf);
  hipLaunchKernelGGL(k_pmm, dim3(64, 16), dim3(256), 0, stream, WcatT, Abt, P3);
  hipLaunchKernelGGL(k_xmm, dim3(64, 32), dim3(256), 0, stream, WcatT, xb, xpre);

  for (int i = 0; i <= 32; ++i){
    const float* sp_rd = spbuf + ((i+1)&1)*4096;
    float*       sp_wr = spbuf + (i&1)*4096;
    hipLaunchKernelGGL(k_gate, dim3(256), dim3(256), 0, stream, i, xpre, a_part, b, P3,
                       A_flat, hbuf, cbuf, sp_rd, sp_wr, hbf, hall);
    if (i < 32)
      hipLaunchKernelGGL(k_mm, dim3(64, 8), dim3(256), 0, stream, WcatT, hbf, a_part);
  }

  hipLaunchKernelGGL(k_score, dim3(2000), dim3(512), 0, stream, WoutT, hall, b_out, pmax, psum);
  hipLaunchKernelGGL(k_nll, dim3(512), dim3(256), 0, stream, hall, WoutT, b_out, captions, pmax, psum, row_loss);
  hipLaunchKernelGGL(k_final, dim3(1), dim3(256), 0, stream, row_loss, out);
}